// Round 5
// baseline (860.675 us; speedup 1.0000x reference)
//
#include <hip/hip_runtime.h>

#define NN 50000
#define NE 800000
#define EP (NE + NN)      // edges + self loops (= 850000 = 16 * 53125)
#define HID 128
#define FIN 64
#define NG 64
#define SLOPE 0.2f
#define STRIP 16          // edges per HALF-wave in k_spmv

__device__ __forceinline__ float wred_sum(float v) {
  for (int off = 32; off; off >>= 1) v += __shfl_xor(v, off);
  return v;
}
__device__ __forceinline__ float wred_max(float v) {
  for (int off = 32; off; off >>= 1) v = fmaxf(v, __shfl_xor(v, off));
  return v;
}

// ---- mean of edge weights -------------------------------------------------
__global__ void k_mean(const float* __restrict__ ew, float* __restrict__ meansum) {
  int tid = blockIdx.x * blockDim.x + threadIdx.x;
  int stride = gridDim.x * blockDim.x;
  float s = 0.f;
  for (int i = tid; i < NE; i += stride) s += ew[i];
  s = wred_sum(s);
  if ((threadIdx.x & 63) == 0) atomicAdd(meansum, s);
}

// ---- histogram of destinations (incl self loops) --------------------------
__global__ void k_hist(const int* __restrict__ edst, int* __restrict__ counts) {
  int tid = blockIdx.x * blockDim.x + threadIdx.x;
  int stride = gridDim.x * blockDim.x;
  for (int i = tid; i < EP; i += stride) {
    int d = (i < NE) ? edst[i] : (i - NE);
    atomicAdd(&counts[d], 1);
  }
}

// ---- single-block exclusive scan; also zeroes counts (reused as cursor) ---
__global__ void k_scan(int* __restrict__ counts, int* __restrict__ starts) {
  __shared__ int wsum[16];
  __shared__ int woff[16];
  int t = threadIdx.x;
  int lane = t & 63;
  int w = t >> 6;
  int carry = 0;
  for (int base = 0; base < NN; base += 1024) {
    int i = base + t;
    int v = (i < NN) ? counts[i] : 0;
    if (i < NN) counts[i] = 0;   // reset cursor for scatter
    int sc = v;
    #pragma unroll
    for (int d = 1; d < 64; d <<= 1) {
      int u = __shfl_up(sc, d);
      if (lane >= d) sc += u;
    }
    if (lane == 63) wsum[w] = sc;
    __syncthreads();
    if (w == 0 && lane < 16) {
      int x = wsum[lane];
      #pragma unroll
      for (int d = 1; d < 16; d <<= 1) {
        int u = __shfl_up(x, d);
        if (lane >= d) x += u;
      }
      woff[lane] = x;   // inclusive scan of wave sums
    }
    __syncthreads();
    int waveoff = (w == 0) ? 0 : woff[w - 1];
    if (i < NN) starts[i] = carry + waveoff + sc - v;
    carry += woff[15];
    __syncthreads();   // protect wsum/woff before next chunk
  }
  if (t == 0) starts[NN] = carry;
}

// ---- scatter edges into dst-sorted order ----------------------------------
__global__ void k_scatter(const int* __restrict__ esrc, const int* __restrict__ edst,
                          const float* __restrict__ ew, const float* __restrict__ meansum,
                          const int* __restrict__ starts, int* __restrict__ cursor,
                          int* __restrict__ srcs, int* __restrict__ dsts,
                          float* __restrict__ wgts) {
  float mw = meansum[0] * (1.0f / NE);
  int tid = blockIdx.x * blockDim.x + threadIdx.x;
  int stride = gridDim.x * blockDim.x;
  for (int i = tid; i < EP; i += stride) {
    int s, d; float wv;
    if (i < NE) { s = esrc[i]; d = edst[i]; wv = ew[i]; }
    else        { s = d = i - NE; wv = mw; }
    int pos = starts[d] + atomicAdd(&cursor[d], 1);
    srcs[pos] = s; dsts[pos] = d; wgts[pos] = wv;
  }
}

// ---- fp32 GEMM: C[n x 128] = A[n x K] @ W[K x 128] + b --------------------
template <int K>
__global__ __launch_bounds__(256) void k_gemm(const float* __restrict__ A,
                                              const float* __restrict__ W,
                                              const float* __restrict__ b,
                                              float* __restrict__ C, int n) {
  __shared__ float As[64][K];
  int t = threadIdx.x;
  int nb = blockIdx.x * 64;
  constexpr int F4 = 16 * K;     // float4 count in the A tile
  for (int i = t; i < F4; i += 256) {
    int row = i / (K / 4);
    int c = (i % (K / 4)) * 4;
    int gn = nb + row;
    float4 v = make_float4(0.f, 0.f, 0.f, 0.f);
    if (gn < n) v = *(const float4*)(A + (size_t)gn * K + c);
    *(float4*)&As[row][c] = v;
  }
  __syncthreads();
  int fx = (t & 31) * 4;
  int ny = (t >> 5) * 8;
  float acc[8][4] = {};
  for (int k = 0; k < K; ++k) {
    float4 wv = *(const float4*)(W + (size_t)k * HID + fx);
    #pragma unroll
    for (int j = 0; j < 8; ++j) {
      float a = As[ny + j][k];
      acc[j][0] += a * wv.x; acc[j][1] += a * wv.y;
      acc[j][2] += a * wv.z; acc[j][3] += a * wv.w;
    }
  }
  float4 bb = *(const float4*)(b + fx);
  #pragma unroll
  for (int j = 0; j < 8; ++j) {
    int gn = nb + ny + j;
    if (gn < n) {
      float4 o = make_float4(acc[j][0] + bb.x, acc[j][1] + bb.y,
                             acc[j][2] + bb.z, acc[j][3] + bb.w);
      *(float4*)(C + (size_t)gn * HID + fx) = o;
    }
  }
}

// ---- per-edge attention logits: 2 edges per wave (half-wave float4) -------
__global__ __launch_bounds__(256) void k_logits(const float* __restrict__ xl,
                                                const float* __restrict__ xr,
                                                const int* __restrict__ srcs,
                                                const int* __restrict__ dsts,
                                                const float* __restrict__ wgts,
                                                const float* __restrict__ We,
                                                const float* __restrict__ att,
                                                float* __restrict__ logits) {
  int gtid = blockIdx.x * blockDim.x + threadIdx.x;
  int wave = gtid >> 6;
  int lane = gtid & 63;
  int half = lane >> 5;          // which edge of the pair
  int hl = lane & 31;            // lane within half
  int nw = (gridDim.x * blockDim.x) >> 6;
  int f = hl * 4;
  float4 we = *(const float4*)(We + f);
  float4 at = *(const float4*)(att + f);
  for (int p0 = wave * 2; p0 < EP; p0 += nw * 2) {
    int p = p0 + half;           // EP even -> always valid
    int s = srcs[p], d = dsts[p];
    float wv = wgts[p];
    float4 a = *(const float4*)(xl + (size_t)s * HID + f);
    float4 b = *(const float4*)(xr + (size_t)d * HID + f);
    float v0 = a.x + b.x + wv * we.x;
    float v1 = a.y + b.y + wv * we.y;
    float v2 = a.z + b.z + wv * we.z;
    float v3 = a.w + b.w + wv * we.w;
    v0 = v0 > 0.f ? v0 : SLOPE * v0;
    v1 = v1 > 0.f ? v1 : SLOPE * v1;
    v2 = v2 > 0.f ? v2 : SLOPE * v2;
    v3 = v3 > 0.f ? v3 : SLOPE * v3;
    float part = v0 * at.x + v1 * at.y + v2 * at.z + v3 * at.w;
    #pragma unroll
    for (int off = 16; off; off >>= 1) part += __shfl_xor(part, off, 32);
    if (hl == 0) logits[p] = part;
  }
}

// ---- per-node softmax: logits -> alpha (in place) --------------------------
__global__ void k_stats(float* __restrict__ logits, const int* __restrict__ starts) {
  int node = blockIdx.x * (blockDim.x >> 6) + (threadIdx.x >> 6);
  int lane = threadIdx.x & 63;
  if (node >= NN) return;
  int s0 = starts[node], s1 = starts[node + 1];
  float m = -1e30f;
  for (int i = s0 + lane; i < s1; i += 64) m = fmaxf(m, logits[i]);
  m = wred_max(m);
  float ssum = 0.f;
  for (int i = s0 + lane; i < s1; i += 64) ssum += __expf(logits[i] - m);
  ssum = wred_sum(ssum);
  float inv = 1.0f / ssum;
  for (int i = s0 + lane; i < s1; i += 64) logits[i] = __expf(logits[i] - m) * inv;
}

// ---- edge-parallel weighted aggregation (16-edge strip per HALF-wave) -----
// EP = 16 * 53125 exactly -> no per-edge tail; only strip-existence guard.
__global__ __launch_bounds__(256) void k_spmv(const float* __restrict__ xl,
                                              const int* __restrict__ srcs,
                                              const int* __restrict__ dsts,
                                              const float* __restrict__ alpha,
                                              float* __restrict__ out) {
  int gtid = blockIdx.x * blockDim.x + threadIdx.x;
  int wave = gtid >> 6;
  int lane = gtid & 63;
  int half = lane >> 5;
  int hl = lane & 31;
  int strip = wave * 2 + half;
  if (strip >= EP / STRIP) return;
  int e0 = strip * STRIP;
  int f = hl * 4;
  int eid = e0 + (hl & (STRIP - 1));
  int s = srcs[eid];
  int d = dsts[eid];
  float a = alpha[eid];
  float4 v[STRIP];
  #pragma unroll
  for (int j = 0; j < STRIP; ++j) {
    int sj = __shfl(s, j, 32);
    v[j] = *(const float4*)(xl + (size_t)sj * HID + f);
  }
  float4 acc = make_float4(0.f, 0.f, 0.f, 0.f);
  int dprev = __shfl(d, 0, 32);
  #pragma unroll
  for (int j = 0; j < STRIP; ++j) {
    int dj = __shfl(d, j, 32);
    float aj = __shfl(a, j, 32);
    if (dj != dprev) {
      float* op = out + (size_t)dprev * HID + f;
      atomicAdd(op + 0, acc.x);
      atomicAdd(op + 1, acc.y);
      atomicAdd(op + 2, acc.z);
      atomicAdd(op + 3, acc.w);
      acc = make_float4(0.f, 0.f, 0.f, 0.f);
      dprev = dj;
    }
    acc.x += aj * v[j].x;
    acc.y += aj * v[j].y;
    acc.z += aj * v[j].z;
    acc.w += aj * v[j].w;
  }
  float* op = out + (size_t)dprev * HID + f;
  atomicAdd(op + 0, acc.x);
  atomicAdd(op + 1, acc.y);
  atomicAdd(op + 2, acc.z);
  atomicAdd(op + 3, acc.w);
}

// ---- bias + relu in place ---------------------------------------------------
__global__ void k_bias(float* __restrict__ agg, const float* __restrict__ bias) {
  int node = blockIdx.x * (blockDim.x >> 6) + (threadIdx.x >> 6);
  int lane = threadIdx.x & 63;
  if (node >= NN) return;
  int f = lane * 2;
  float2 v = *(const float2*)(agg + (size_t)node * HID + f);
  v.x = fmaxf(v.x + bias[f], 0.f);
  v.y = fmaxf(v.y + bias[f + 1], 0.f);
  *(float2*)(agg + (size_t)node * HID + f) = v;
}

// ---- graph boundaries from sorted batch ------------------------------------
__global__ void k_bounds(const int* __restrict__ batch, int* __restrict__ gs) {
  int i = blockIdx.x * blockDim.x + threadIdx.x;
  if (i >= NN) return;
  int b = batch[i];
  if (i == 0) {
    for (int g = 0; g <= b; ++g) gs[g] = 0;
  }
  int bn = (i + 1 < NN) ? batch[i + 1] : NG;
  for (int g = b + 1; g <= bn; ++g) gs[g] = i + 1;
}

// ---- segmented mean pool + final linear (one block per graph) --------------
__global__ __launch_bounds__(256) void k_pool(const float* __restrict__ h,
                                              const int* __restrict__ gs,
                                              const float* __restrict__ Wlin,
                                              const float* __restrict__ blin,
                                              float* __restrict__ out) {
  __shared__ float red[256];
  int g = blockIdx.x;
  int t = threadIdx.x;
  int f = t & 127;
  int half = t >> 7;           // 0 or 1
  int n0 = gs[g], n1 = gs[g + 1];
  float s0 = 0.f, s1 = 0.f, s2 = 0.f, s3 = 0.f;
  int n = n0 + half;
  for (; n + 6 < n1; n += 8) {
    s0 += h[(size_t)n * HID + f];
    s1 += h[(size_t)(n + 2) * HID + f];
    s2 += h[(size_t)(n + 4) * HID + f];
    s3 += h[(size_t)(n + 6) * HID + f];
  }
  for (; n < n1; n += 2) s0 += h[(size_t)n * HID + f];
  red[t] = (s0 + s1) + (s2 + s3);
  __syncthreads();
  if (t < 128) {
    float pooled = red[t] + red[t + 128];
    float cnt = (float)max(n1 - n0, 1);
    red[t] = (pooled / cnt) * Wlin[f];
  }
  __syncthreads();
  if (t < 64) {
    float v = red[t] + red[t + 64];
    v = wred_sum(v);
    if (t == 0) out[g] = v + blin[0];
  }
}

extern "C" void kernel_launch(void* const* d_in, const int* in_sizes, int n_in,
                              void* d_out, int out_size, void* d_ws, size_t ws_size,
                              hipStream_t stream) {
  const float* x     = (const float*)d_in[0];
  const int*   ei    = (const int*)d_in[1];      // [2][NE]
  const float* ew    = (const float*)d_in[2];
  const int*   batch = (const int*)d_in[3];
  const float* W1l = (const float*)d_in[4];
  const float* b1l = (const float*)d_in[5];
  const float* W1r = (const float*)d_in[6];
  const float* b1r = (const float*)d_in[7];
  const float* We1 = (const float*)d_in[8];
  const float* at1 = (const float*)d_in[9];
  const float* bi1 = (const float*)d_in[10];
  const float* W2l = (const float*)d_in[11];
  const float* b2l = (const float*)d_in[12];
  const float* W2r = (const float*)d_in[13];
  const float* b2r = (const float*)d_in[14];
  const float* We2 = (const float*)d_in[15];
  const float* at2 = (const float*)d_in[16];
  const float* bi2 = (const float*)d_in[17];
  const float* Wlin = (const float*)d_in[18];
  const float* blin = (const float*)d_in[19];

  float* ws = (float*)d_ws;
  size_t o = 0;
  float* xl     = ws + o; o += (size_t)NN * HID;
  float* xr     = ws + o; o += (size_t)NN * HID;
  float* hb     = ws + o; o += (size_t)NN * HID;
  float* logits = ws + o; o += EP;            // becomes alpha in place
  float* wgts   = ws + o; o += EP;
  int*   srcs   = (int*)(ws + o); o += EP;
  int*   dsts   = (int*)(ws + o); o += EP;
  int*   starts = (int*)(ws + o); o += NN + 1;
  int*   gs     = (int*)(ws + o); o += NG + 1;
  size_t zoff = o;
  int*   counts    = (int*)(ws + o); o += NN;
  float* meansum   = ws + o; o += 1;
  size_t zero_bytes = (o - zoff) * sizeof(float);

  hipMemsetAsync(counts, 0, zero_bytes, stream);

  // build dst-sorted CSR (shared by both layers) + graph bounds
  k_mean<<<256, 256, 0, stream>>>(ew, meansum);
  k_hist<<<1024, 256, 0, stream>>>(ei + NE, counts);
  k_scan<<<1, 1024, 0, stream>>>(counts, starts);
  k_scatter<<<1024, 256, 0, stream>>>(ei, ei + NE, ew, meansum, starts, counts,
                                      srcs, dsts, wgts);
  k_bounds<<<(NN + 255) / 256, 256, 0, stream>>>(batch, gs);

  int gb  = (NN + 63) / 64;                       // gemm blocks
  int nbn = (NN + 3) / 4;                         // node-per-wave blocks
  int nstrips = EP / STRIP;                       // 53125
  int sbn = (nstrips / 2 + 4) / 4;                // 2 strips per wave, 4 waves/block
  size_t hbytes = (size_t)NN * HID * sizeof(float);

  // layer 1
  k_gemm<FIN><<<gb, 256, 0, stream>>>(x, W1l, b1l, xl, NN);
  k_gemm<FIN><<<gb, 256, 0, stream>>>(x, W1r, b1r, xr, NN);
  k_logits<<<4096, 256, 0, stream>>>(xl, xr, srcs, dsts, wgts, We1, at1, logits);
  k_stats<<<nbn, 256, 0, stream>>>(logits, starts);
  hipMemsetAsync(hb, 0, hbytes, stream);
  k_spmv<<<sbn, 256, 0, stream>>>(xl, srcs, dsts, logits, hb);
  k_bias<<<nbn, 256, 0, stream>>>(hb, bi1);
  // layer 2
  k_gemm<HID><<<gb, 256, 0, stream>>>(hb, W2l, b2l, xl, NN);
  k_gemm<HID><<<gb, 256, 0, stream>>>(hb, W2r, b2r, xr, NN);
  k_logits<<<4096, 256, 0, stream>>>(xl, xr, srcs, dsts, wgts, We2, at2, logits);
  k_stats<<<nbn, 256, 0, stream>>>(logits, starts);
  hipMemsetAsync(hb, 0, hbytes, stream);          // hb already consumed by gemm2
  k_spmv<<<sbn, 256, 0, stream>>>(xl, srcs, dsts, logits, hb);
  k_bias<<<nbn, 256, 0, stream>>>(hb, bi2);
  // pool + head (no atomics: batch is sorted -> contiguous graph ranges)
  k_pool<<<NG, 256, 0, stream>>>(hb, gs, Wlin, blin, (float*)d_out);
}

// Round 6
// 578.027 us; speedup vs baseline: 1.4890x; 1.4890x over previous
//
#include <hip/hip_runtime.h>

#define NN 50000
#define NE 800000
#define EP (NE + NN)      // edges + self loops (= 850000)
#define HID 128
#define FIN 64
#define NG 64
#define SLOPE 0.2f

__device__ __forceinline__ float wred_sum(float v) {
  for (int off = 32; off; off >>= 1) v += __shfl_xor(v, off);
  return v;
}
__device__ __forceinline__ float wred_max(float v) {
  for (int off = 32; off; off >>= 1) v = fmaxf(v, __shfl_xor(v, off));
  return v;
}

// ---- mean of edge weights -------------------------------------------------
__global__ void k_mean(const float* __restrict__ ew, float* __restrict__ meansum) {
  int tid = blockIdx.x * blockDim.x + threadIdx.x;
  int stride = gridDim.x * blockDim.x;
  float s = 0.f;
  for (int i = tid; i < NE; i += stride) s += ew[i];
  s = wred_sum(s);
  if ((threadIdx.x & 63) == 0) atomicAdd(meansum, s);
}

// ---- histogram of destinations (incl self loops) --------------------------
__global__ void k_hist(const int* __restrict__ edst, int* __restrict__ counts) {
  int tid = blockIdx.x * blockDim.x + threadIdx.x;
  int stride = gridDim.x * blockDim.x;
  for (int i = tid; i < EP; i += stride) {
    int d = (i < NE) ? edst[i] : (i - NE);
    atomicAdd(&counts[d], 1);
  }
}

// ---- single-block exclusive scan; also zeroes counts (reused as cursor) ---
__global__ void k_scan(int* __restrict__ counts, int* __restrict__ starts) {
  __shared__ int wsum[16];
  __shared__ int woff[16];
  int t = threadIdx.x;
  int lane = t & 63;
  int w = t >> 6;
  int carry = 0;
  for (int base = 0; base < NN; base += 1024) {
    int i = base + t;
    int v = (i < NN) ? counts[i] : 0;
    if (i < NN) counts[i] = 0;   // reset cursor for scatter
    int sc = v;
    #pragma unroll
    for (int d = 1; d < 64; d <<= 1) {
      int u = __shfl_up(sc, d);
      if (lane >= d) sc += u;
    }
    if (lane == 63) wsum[w] = sc;
    __syncthreads();
    if (w == 0 && lane < 16) {
      int x = wsum[lane];
      #pragma unroll
      for (int d = 1; d < 16; d <<= 1) {
        int u = __shfl_up(x, d);
        if (lane >= d) x += u;
      }
      woff[lane] = x;   // inclusive scan of wave sums
    }
    __syncthreads();
    int waveoff = (w == 0) ? 0 : woff[w - 1];
    if (i < NN) starts[i] = carry + waveoff + sc - v;
    carry += woff[15];
    __syncthreads();   // protect wsum/woff before next chunk
  }
  if (t == 0) starts[NN] = carry;
}

// ---- scatter edges into dst-sorted order ----------------------------------
__global__ void k_scatter(const int* __restrict__ esrc, const int* __restrict__ edst,
                          const float* __restrict__ ew, const float* __restrict__ meansum,
                          const int* __restrict__ starts, int* __restrict__ cursor,
                          int* __restrict__ srcs, int* __restrict__ dsts,
                          float* __restrict__ wgts) {
  float mw = meansum[0] * (1.0f / NE);
  int tid = blockIdx.x * blockDim.x + threadIdx.x;
  int stride = gridDim.x * blockDim.x;
  for (int i = tid; i < EP; i += stride) {
    int s, d; float wv;
    if (i < NE) { s = esrc[i]; d = edst[i]; wv = ew[i]; }
    else        { s = d = i - NE; wv = mw; }
    int pos = starts[d] + atomicAdd(&cursor[d], 1);
    srcs[pos] = s; dsts[pos] = d; wgts[pos] = wv;
  }
}

// ---- fp32 GEMM: C[n x 128] = A[n x K] @ W[K x 128] + b --------------------
template <int K>
__global__ __launch_bounds__(256) void k_gemm(const float* __restrict__ A,
                                              const float* __restrict__ W,
                                              const float* __restrict__ b,
                                              float* __restrict__ C, int n) {
  __shared__ float As[64][K];
  int t = threadIdx.x;
  int nb = blockIdx.x * 64;
  constexpr int F4 = 16 * K;     // float4 count in the A tile
  for (int i = t; i < F4; i += 256) {
    int row = i / (K / 4);
    int c = (i % (K / 4)) * 4;
    int gn = nb + row;
    float4 v = make_float4(0.f, 0.f, 0.f, 0.f);
    if (gn < n) v = *(const float4*)(A + (size_t)gn * K + c);
    *(float4*)&As[row][c] = v;
  }
  __syncthreads();
  int fx = (t & 31) * 4;
  int ny = (t >> 5) * 8;
  float acc[8][4] = {};
  for (int k = 0; k < K; ++k) {
    float4 wv = *(const float4*)(W + (size_t)k * HID + fx);
    #pragma unroll
    for (int j = 0; j < 8; ++j) {
      float a = As[ny + j][k];
      acc[j][0] += a * wv.x; acc[j][1] += a * wv.y;
      acc[j][2] += a * wv.z; acc[j][3] += a * wv.w;
    }
  }
  float4 bb = *(const float4*)(b + fx);
  #pragma unroll
  for (int j = 0; j < 8; ++j) {
    int gn = nb + ny + j;
    if (gn < n) {
      float4 o = make_float4(acc[j][0] + bb.x, acc[j][1] + bb.y,
                             acc[j][2] + bb.z, acc[j][3] + bb.w);
      *(float4*)(C + (size_t)gn * HID + fx) = o;
    }
  }
}

// ---- per-edge attention logits: 2 edges per wave (half-wave float4) -------
__global__ __launch_bounds__(256) void k_logits(const float* __restrict__ xl,
                                                const float* __restrict__ xr,
                                                const int* __restrict__ srcs,
                                                const int* __restrict__ dsts,
                                                const float* __restrict__ wgts,
                                                const float* __restrict__ We,
                                                const float* __restrict__ att,
                                                float* __restrict__ logits) {
  int gtid = blockIdx.x * blockDim.x + threadIdx.x;
  int wave = gtid >> 6;
  int lane = gtid & 63;
  int half = lane >> 5;          // which edge of the pair
  int hl = lane & 31;            // lane within half
  int nw = (gridDim.x * blockDim.x) >> 6;
  int f = hl * 4;
  float4 we = *(const float4*)(We + f);
  float4 at = *(const float4*)(att + f);
  for (int p0 = wave * 2; p0 < EP; p0 += nw * 2) {
    int p = p0 + half;           // EP even -> always valid
    int s = srcs[p], d = dsts[p];
    float wv = wgts[p];
    float4 a = *(const float4*)(xl + (size_t)s * HID + f);
    float4 b = *(const float4*)(xr + (size_t)d * HID + f);
    float v0 = a.x + b.x + wv * we.x;
    float v1 = a.y + b.y + wv * we.y;
    float v2 = a.z + b.z + wv * we.z;
    float v3 = a.w + b.w + wv * we.w;
    v0 = v0 > 0.f ? v0 : SLOPE * v0;
    v1 = v1 > 0.f ? v1 : SLOPE * v1;
    v2 = v2 > 0.f ? v2 : SLOPE * v2;
    v3 = v3 > 0.f ? v3 : SLOPE * v3;
    float part = v0 * at.x + v1 * at.y + v2 * at.z + v3 * at.w;
    #pragma unroll
    for (int off = 16; off; off >>= 1) part += __shfl_xor(part, off, 32);
    if (hl == 0) logits[p] = part;
  }
}

// ---- fused softmax + aggregation + bias + relu (node per wave) -------------
// Stats lane-parallel over the node's CSR range; gathers issued 16-deep with
// lane-parallel metadata (no scalar-load chains); single plain store/node.
__global__ __launch_bounds__(256) void k_aggf(const float* __restrict__ xl,
                                              const float* __restrict__ logits,
                                              const int* __restrict__ srcs,
                                              const int* __restrict__ starts,
                                              const float* __restrict__ bias,
                                              float* __restrict__ hout) {
  int node = blockIdx.x * (blockDim.x >> 6) + (threadIdx.x >> 6);
  int lane = threadIdx.x & 63;
  if (node >= NN) return;
  int s0 = starts[node], s1 = starts[node + 1];
  // softmax stats (deg ~17 -> one iteration)
  float m = -1e30f;
  for (int i = s0 + lane; i < s1; i += 64) m = fmaxf(m, logits[i]);
  m = wred_max(m);
  float ssum = 0.f;
  for (int i = s0 + lane; i < s1; i += 64) ssum += __expf(logits[i] - m);
  ssum = wred_sum(ssum);
  float inv = 1.0f / ssum;

  int f = lane * 2;
  float a0 = 0.f, a1 = 0.f;
  for (int i0 = s0; i0 < s1; i0 += 16) {
    // each 16-lane group loads the same 16 edges' metadata in parallel
    int e = i0 + (lane & 15);
    int idx = min(e, s1 - 1);            // clamp; invalid k gets weight 0
    int sv = srcs[idx];
    float al = __expf(logits[idx] - m);
    float2 v[16];
    #pragma unroll
    for (int k = 0; k < 16; ++k) {
      int sj = __shfl(sv, k, 16);
      v[k] = *(const float2*)(xl + (size_t)sj * HID + f);
    }
    #pragma unroll
    for (int k = 0; k < 16; ++k) {
      float ak = (i0 + k < s1) ? __shfl(al, k, 16) : 0.f;
      a0 += ak * v[k].x;
      a1 += ak * v[k].y;
    }
  }
  a0 = fmaxf(a0 * inv + bias[f], 0.f);
  a1 = fmaxf(a1 * inv + bias[f + 1], 0.f);
  *(float2*)(hout + (size_t)node * HID + f) = make_float2(a0, a1);
}

// ---- graph boundaries from sorted batch ------------------------------------
__global__ void k_bounds(const int* __restrict__ batch, int* __restrict__ gs) {
  int i = blockIdx.x * blockDim.x + threadIdx.x;
  if (i >= NN) return;
  int b = batch[i];
  if (i == 0) {
    for (int g = 0; g <= b; ++g) gs[g] = 0;
  }
  int bn = (i + 1 < NN) ? batch[i + 1] : NG;
  for (int g = b + 1; g <= bn; ++g) gs[g] = i + 1;
}

// ---- segmented mean pool + final linear (one block per graph) --------------
__global__ __launch_bounds__(256) void k_pool(const float* __restrict__ h,
                                              const int* __restrict__ gs,
                                              const float* __restrict__ Wlin,
                                              const float* __restrict__ blin,
                                              float* __restrict__ out) {
  __shared__ float red[256];
  int g = blockIdx.x;
  int t = threadIdx.x;
  int f = t & 127;
  int half = t >> 7;           // 0 or 1
  int n0 = gs[g], n1 = gs[g + 1];
  float s0 = 0.f, s1 = 0.f, s2 = 0.f, s3 = 0.f;
  int n = n0 + half;
  for (; n + 6 < n1; n += 8) {
    s0 += h[(size_t)n * HID + f];
    s1 += h[(size_t)(n + 2) * HID + f];
    s2 += h[(size_t)(n + 4) * HID + f];
    s3 += h[(size_t)(n + 6) * HID + f];
  }
  for (; n < n1; n += 2) s0 += h[(size_t)n * HID + f];
  red[t] = (s0 + s1) + (s2 + s3);
  __syncthreads();
  if (t < 128) {
    float pooled = red[t] + red[t + 128];
    float cnt = (float)max(n1 - n0, 1);
    red[t] = (pooled / cnt) * Wlin[f];
  }
  __syncthreads();
  if (t < 64) {
    float v = red[t] + red[t + 64];
    v = wred_sum(v);
    if (t == 0) out[g] = v + blin[0];
  }
}

extern "C" void kernel_launch(void* const* d_in, const int* in_sizes, int n_in,
                              void* d_out, int out_size, void* d_ws, size_t ws_size,
                              hipStream_t stream) {
  const float* x     = (const float*)d_in[0];
  const int*   ei    = (const int*)d_in[1];      // [2][NE]
  const float* ew    = (const float*)d_in[2];
  const int*   batch = (const int*)d_in[3];
  const float* W1l = (const float*)d_in[4];
  const float* b1l = (const float*)d_in[5];
  const float* W1r = (const float*)d_in[6];
  const float* b1r = (const float*)d_in[7];
  const float* We1 = (const float*)d_in[8];
  const float* at1 = (const float*)d_in[9];
  const float* bi1 = (const float*)d_in[10];
  const float* W2l = (const float*)d_in[11];
  const float* b2l = (const float*)d_in[12];
  const float* W2r = (const float*)d_in[13];
  const float* b2r = (const float*)d_in[14];
  const float* We2 = (const float*)d_in[15];
  const float* at2 = (const float*)d_in[16];
  const float* bi2 = (const float*)d_in[17];
  const float* Wlin = (const float*)d_in[18];
  const float* blin = (const float*)d_in[19];

  float* ws = (float*)d_ws;
  size_t o = 0;
  float* xl     = ws + o; o += (size_t)NN * HID;
  float* xr     = ws + o; o += (size_t)NN * HID;
  float* hb     = ws + o; o += (size_t)NN * HID;
  float* logits = ws + o; o += EP;
  float* wgts   = ws + o; o += EP;
  int*   srcs   = (int*)(ws + o); o += EP;
  int*   dsts   = (int*)(ws + o); o += EP;
  int*   starts = (int*)(ws + o); o += NN + 1;
  int*   gs     = (int*)(ws + o); o += NG + 1;
  size_t zoff = o;
  int*   counts    = (int*)(ws + o); o += NN;
  float* meansum   = ws + o; o += 1;
  size_t zero_bytes = (o - zoff) * sizeof(float);

  hipMemsetAsync(counts, 0, zero_bytes, stream);

  // build dst-sorted CSR (shared by both layers) + graph bounds
  k_mean<<<256, 256, 0, stream>>>(ew, meansum);
  k_hist<<<1024, 256, 0, stream>>>(ei + NE, counts);
  k_scan<<<1, 1024, 0, stream>>>(counts, starts);
  k_scatter<<<1024, 256, 0, stream>>>(ei, ei + NE, ew, meansum, starts, counts,
                                      srcs, dsts, wgts);
  k_bounds<<<(NN + 255) / 256, 256, 0, stream>>>(batch, gs);

  int gb  = (NN + 63) / 64;                       // gemm blocks
  int nbn = (NN + 3) / 4;                         // node-per-wave blocks

  // layer 1
  k_gemm<FIN><<<gb, 256, 0, stream>>>(x, W1l, b1l, xl, NN);
  k_gemm<FIN><<<gb, 256, 0, stream>>>(x, W1r, b1r, xr, NN);
  k_logits<<<4096, 256, 0, stream>>>(xl, xr, srcs, dsts, wgts, We1, at1, logits);
  k_aggf<<<nbn, 256, 0, stream>>>(xl, logits, srcs, starts, bi1, hb);
  // layer 2
  k_gemm<HID><<<gb, 256, 0, stream>>>(hb, W2l, b2l, xl, NN);
  k_gemm<HID><<<gb, 256, 0, stream>>>(hb, W2r, b2r, xr, NN);
  k_logits<<<4096, 256, 0, stream>>>(xl, xr, srcs, dsts, wgts, We2, at2, logits);
  k_aggf<<<nbn, 256, 0, stream>>>(xl, logits, srcs, starts, bi2, hb);
  // pool + head (no atomics: batch is sorted -> contiguous graph ranges)
  k_pool<<<NG, 256, 0, stream>>>(hb, gs, Wlin, blin, (float*)d_out);
}